// Round 5
// baseline (1902.518 us; speedup 1.0000x reference)
//
#include <hip/hip_runtime.h>
#include <stdint.h>

typedef unsigned short u16;
typedef unsigned int u32;
typedef __attribute__((ext_vector_type(8))) __bf16 bf16x8;
typedef __attribute__((ext_vector_type(4))) float f32x4;

#define DEVINL static __device__ __forceinline__

// round-to-nearest-even f32 -> bf16
DEVINL u16 f2bf(float x) {
  u32 u = __float_as_uint(x);
  return (u16)((u + (((u >> 16) & 1u) + 0x7fffu)) >> 16);
}
DEVINL float bf2f(u16 h) { return __uint_as_float(((u32)h) << 16); }

// async global->LDS, 16B per lane. HW semantics: wave-uniform base + lane*16;
// our per-lane pointers are exactly waveBase + lane*16 (m97 pattern).
DEVINL void async16(const void* g, void* l) {
  void* g2 = const_cast<void*>(g);
  __builtin_amdgcn_global_load_lds((__attribute__((address_space(1))) void*)g2,
                                   (__attribute__((address_space(3))) void*)l,
                                   16, 0, 0);
}

// ============================ pack kernels ============================
// Pads weight [n,k] f32 into [NP,KP] bf16 hi (+ optional lo = x - hi).
// gap=1 remaps dst col c>=640 -> src col c-40 (combined layout has a
// 40-col zero gap at 600..639), cols 600..639 -> 0.
__global__ void k_pack_w(const float* src, int n, int k, u16* hi, u16* lo,
                         int KP, long total, int gap) {
  long i = (long)blockIdx.x * 256 + threadIdx.x;
  if (i >= total) return;
  int r = (int)(i / KP);
  int c = (int)(i - (long)r * KP);
  int sc = c;
  bool ok = (r < n);
  if (gap) {
    if (c >= 600 && c < 640) ok = false;
    else if (c >= 640) sc = c - 40;
  }
  if (sc >= k) ok = false;
  float x = ok ? src[(size_t)r * k + sc] : 0.f;
  u16 h = f2bf(x);
  hi[i] = h;
  if (lo) lo[i] = f2bf(x - bf2f(h));
}

__global__ void k_pack_bias(const float* src, int n, float* dst, int NP) {
  int i = blockIdx.x * 256 + threadIdx.x;
  if (i < NP) dst[i] = (i < n) ? src[i] : 0.f;
}

// ============ bb_process + concat(s, bb) -> combined[:, 0:640] ============
// s_c / ps_c are chunk-local (host pre-offset). blockIdx.x = local row.
__global__ void k_bb(const float* s_c, const float* ps_c, const float* bb_w,
                     const float* bb_b, u16* Chi, u16* Clo) {
  int rn = blockIdx.x;
  const float* p = ps_c + (size_t)rn * 4;
  float p0 = p[0], p1 = p[1], p2 = p[2], p3 = p[3];
  float sz0 = p2 - p0, sz1 = p3 - p1;
  float bin[10];
  bin[0] = p0; bin[1] = p1; bin[2] = p2; bin[3] = p3;
  bin[4] = sz0; bin[5] = sz1;
  bin[6] = p0 + 0.5f * sz0; bin[7] = p1 + 0.5f * sz1;
  bin[8] = sz0 * sz1; bin[9] = sz0 / (sz1 + 1e-14f);
  for (int c = threadIdx.x; c < 640; c += 256) {
    float x = 0.f;
    if (c < 300) {
      x = s_c[(size_t)rn * 300 + c];
    } else if (c < 600) {
      int j = c - 300;
      float a = bb_b[j];
      const float* wr = bb_w + j * 10;
#pragma unroll
      for (int kk = 0; kk < 10; ++kk) a += bin[kk] * wr[kk];
      x = fmaxf(a, 0.f);
    }
    u16 h = f2bf(x);
    Chi[(size_t)rn * 1280 + c] = h;
    Clo[(size_t)rn * 1280 + c] = f2bf(x - bf2f(h));
  }
}

// ============================ GEMM core ============================
// 128x128 tile, BK=32, 4 waves x (4x4) 16x16x32 bf16 MFMA, C = A @ W^T.
// passes=3 runs phases {Ahi*Whi, Alo*Whi, Ahi*Wlo} for ~f32 precision.
DEVINL void gemm_core(const u16* const Aph[3], const u16* const Bph[3],
                      int lda, int ldw, int ksteps, int passes,
                      u16* As, u16* Bs, f32x4 (&acc)[4][4]) {
  const int tid = threadIdx.x;
  const int lane = tid & 63;
  const int wv = tid >> 6;
  const int wr = (wv >> 1) * 64;
  const int wc = (wv & 1) * 64;
  const int mrow = lane & 15;
  const int q = lane >> 4;

  const int c0 = tid, c1 = tid + 256;  // 512 x 16B chunks per 8KB tile
  const long aoff0 = (long)(c0 >> 2) * lda + (c0 & 3) * 8;
  const long aoff1 = (long)(c1 >> 2) * lda + (c1 & 3) * 8;
  const long boff0 = (long)(c0 >> 2) * ldw + (c0 & 3) * 8;
  const long boff1 = (long)(c1 >> 2) * ldw + (c1 & 3) * 8;
  u16* lA0 = As + c0 * 8; u16* lA1 = As + c1 * 8;
  u16* lB0 = Bs + c0 * 8; u16* lB1 = Bs + c1 * 8;

  const int aF = (wr + mrow) * 32 + q * 8;
  const int bF = (wc + mrow) * 32 + q * 8;

  for (int p = 0; p < passes; ++p) {
    const u16* Ab = Aph[p];
    const u16* Bb = Bph[p];
    for (int t = 0; t < ksteps; ++t) {
      const u16* ga = Ab + t * 32;
      const u16* gb = Bb + t * 32;
      __syncthreads();
      async16(ga + aoff0, lA0);
      async16(ga + aoff1, lA1);
      async16(gb + boff0, lB0);
      async16(gb + boff1, lB1);
      __syncthreads();
      bf16x8 af[4], bv[4];
#pragma unroll
      for (int i = 0; i < 4; ++i) af[i] = *(const bf16x8*)(As + aF + i * 512);
#pragma unroll
      for (int i = 0; i < 4; ++i) bv[i] = *(const bf16x8*)(Bs + bF + i * 512);
#pragma unroll
      for (int i = 0; i < 4; ++i)
#pragma unroll
        for (int j = 0; j < 4; ++j)
          acc[i][j] = __builtin_amdgcn_mfma_f32_16x16x32_bf16(af[i], bv[j],
                                                              acc[i][j], 0, 0, 0);
    }
  }
}

#define GEMM_PROLOGUE(LDA, LDW)                                         \
  __shared__ __align__(16) u16 As[4096], Bs[4096];                      \
  const u16* Aph[3]; const u16* Bph[3];                                 \
  const size_t arow = (size_t)blockIdx.y * 128 * (LDA);                 \
  const size_t wrow = (size_t)blockIdx.x * 128 * (LDW);                 \
  f32x4 acc[4][4] = {};

#define GEMM_EPI_IDX                                                    \
  const int lane = threadIdx.x & 63, wv = threadIdx.x >> 6;             \
  const int wr = (wv >> 1) * 64, wc = (wv & 1) * 64;                    \
  const int mcol = lane & 15, q = lane >> 4;                            \
  const int gm0 = blockIdx.y * 128, gn0 = blockIdx.x * 128;

// fa1: out = relu(combined[:, :640] @ Wfa1^T + b), f32, 3-pass
__global__ __launch_bounds__(256) void k_gemm_fa1(const u16* Ah, const u16* Al,
    const u16* Wh, const u16* Wl, const float* bias, float* outp) {
  GEMM_PROLOGUE(1280, 640)
  Aph[0] = Ah + arow; Aph[1] = Al + arow; Aph[2] = Ah + arow;
  Bph[0] = Wh + wrow; Bph[1] = Wh + wrow; Bph[2] = Wl + wrow;
  gemm_core(Aph, Bph, 1280, 640, 20, 3, As, Bs, acc);
  GEMM_EPI_IDX
#pragma unroll
  for (int mi = 0; mi < 4; ++mi)
#pragma unroll
    for (int r = 0; r < 4; ++r) {
      int grow = gm0 + wr + mi * 16 + q * 4 + r;
#pragma unroll
      for (int ni = 0; ni < 4; ++ni) {
        int gcol = gn0 + wc + ni * 16 + mcol;
        outp[(size_t)grow * 640 + gcol] = fmaxf(acc[mi][ni][r] + bias[gcol], 0.f);
      }
    }
}

// fa2: y = relu(A@Wfa2^T+b) * fa1o ; split -> combined[:, 640+j] hi/lo
__global__ __launch_bounds__(256) void k_gemm_fa2(const u16* Ah, const u16* Al,
    const u16* Wh, const u16* Wl, const float* bias, const float* fa1o,
    u16* Chi, u16* Clo) {
  GEMM_PROLOGUE(1280, 640)
  Aph[0] = Ah + arow; Aph[1] = Al + arow; Aph[2] = Ah + arow;
  Bph[0] = Wh + wrow; Bph[1] = Wh + wrow; Bph[2] = Wl + wrow;
  gemm_core(Aph, Bph, 1280, 640, 20, 3, As, Bs, acc);
  GEMM_EPI_IDX
#pragma unroll
  for (int mi = 0; mi < 4; ++mi)
#pragma unroll
    for (int r = 0; r < 4; ++r) {
      int grow = gm0 + wr + mi * 16 + q * 4 + r;
#pragma unroll
      for (int ni = 0; ni < 4; ++ni) {
        int gcol = gn0 + wc + ni * 16 + mcol;
        float y = fmaxf(acc[mi][ni][r] + bias[gcol], 0.f) *
                  fa1o[(size_t)grow * 640 + gcol];
        u16 h = f2bf(y);
        Chi[(size_t)grow * 1280 + 640 + gcol] = h;
        Clo[(size_t)grow * 1280 + 640 + gcol] = f2bf(y - bf2f(h));
      }
    }
}

// lp: [512,2048] @ [2560,2048]^T, 3-pass, relu -> f32 [512,2560]
__global__ __launch_bounds__(256) void k_gemm_lp(const u16* Ah, const u16* Al,
    const u16* Wh, const u16* Wl, const float* bias, float* outp) {
  GEMM_PROLOGUE(2048, 2048)
  Aph[0] = Ah + arow; Aph[1] = Al + arow; Aph[2] = Ah + arow;
  Bph[0] = Wh + wrow; Bph[1] = Wh + wrow; Bph[2] = Wl + wrow;
  gemm_core(Aph, Bph, 2048, 2048, 64, 3, As, Bs, acc);
  GEMM_EPI_IDX
#pragma unroll
  for (int mi = 0; mi < 4; ++mi)
#pragma unroll
    for (int r = 0; r < 4; ++r) {
      int grow = gm0 + wr + mi * 16 + q * 4 + r;
#pragma unroll
      for (int ni = 0; ni < 4; ++ni) {
        int gcol = gn0 + wc + ni * 16 + mcol;
        outp[(size_t)grow * 2560 + gcol] = fmaxf(acc[mi][ni][r] + bias[gcol], 0.f);
      }
    }
}

// fa3+fa4 fused (N=2560), 3-pass. fa3 (cols<1280): *lp1 -> fa3 hi/lo;
// fa4 -> fa4 hi/lo. r0 = global row offset of this chunk.
__global__ __launch_bounds__(256) void k_gemm_fa34(const u16* Ah, const u16* Al,
    const u16* Wh, const u16* Wl, const float* bias, const float* lp_o,
    u16* fa3h, u16* fa3l, u16* fa4h, u16* fa4l, int r0) {
  GEMM_PROLOGUE(1280, 1280)
  Aph[0] = Ah + arow; Aph[1] = Al + arow; Aph[2] = Ah + arow;
  Bph[0] = Wh + wrow; Bph[1] = Wh + wrow; Bph[2] = Wl + wrow;
  gemm_core(Aph, Bph, 1280, 1280, 40, 3, As, Bs, acc);
  GEMM_EPI_IDX
  const int seg = (gn0 >= 1280);  // block-uniform (tiles don't straddle)
  u16* dsth = seg ? fa4h : fa3h;
  u16* dstl = seg ? fa4l : fa3l;
#pragma unroll
  for (int mi = 0; mi < 4; ++mi)
#pragma unroll
    for (int r = 0; r < 4; ++r) {
      int grow = gm0 + wr + mi * 16 + q * 4 + r;
      int b = (r0 + grow) / 50;
      const float* lpb = lp_o + (size_t)b * 2560;
#pragma unroll
      for (int ni = 0; ni < 4; ++ni) {
        int gcol = gn0 + wc + ni * 16 + mcol;
        int c = seg ? gcol - 1280 : gcol;
        float v = fmaxf(acc[mi][ni][r] + bias[gcol], 0.f);
        if (!seg) v *= lpb[c];
        if (c < 1216) {
          u16 h = f2bf(v);
          dsth[(size_t)grow * 1216 + c] = h;
          dstl[(size_t)grow * 1216 + c] = f2bf(v - bf2f(h));
        }
      }
    }
}

// fa5 (prepared), 1-pass: relu(A@W^T+b) * lp2 -> bf16 [RN,1216]
__global__ __launch_bounds__(256) void k_gemm_fa5(const u16* Ah, const u16* Wh,
    const float* bias, const float* lp_o, u16* fa5o, int r0) {
  GEMM_PROLOGUE(1280, 1280)
  Aph[0] = Ah + arow; Aph[1] = Ah + arow; Aph[2] = Ah + arow;
  Bph[0] = Wh + wrow; Bph[1] = Wh + wrow; Bph[2] = Wh + wrow;
  gemm_core(Aph, Bph, 1280, 1280, 40, 1, As, Bs, acc);
  GEMM_EPI_IDX
#pragma unroll
  for (int mi = 0; mi < 4; ++mi)
#pragma unroll
    for (int r = 0; r < 4; ++r) {
      int grow = gm0 + wr + mi * 16 + q * 4 + r;
      int b = (r0 + grow) / 50;
      const float* lpb = lp_o + (size_t)b * 2560 + 1280;
#pragma unroll
      for (int ni = 0; ni < 4; ++ni) {
        int gcol = gn0 + wc + ni * 16 + mcol;
        float v = fmaxf(acc[mi][ni][r] + bias[gcol], 0.f) * lpb[gcol];
        if (gcol < 1216) fa5o[(size_t)grow * 1216 + gcol] = f2bf(v);
      }
    }
}

// out FC, 1-pass: messages = relu(msg@outw^T+b), masked, -> d_out cols 300..599
__global__ __launch_bounds__(256) void k_gemm_out(const u16* A, const u16* Wh,
    const float* bias, const int* mask_s, float* outp, int r0) {
  GEMM_PROLOGUE(1216, 1216)
  Aph[0] = A + arow; Aph[1] = A + arow; Aph[2] = A + arow;
  Bph[0] = Wh + wrow; Bph[1] = Wh + wrow; Bph[2] = Wh + wrow;
  gemm_core(Aph, Bph, 1216, 1216, 38, 1, As, Bs, acc);
  GEMM_EPI_IDX
#pragma unroll
  for (int mi = 0; mi < 4; ++mi)
#pragma unroll
    for (int r = 0; r < 4; ++r) {
      int grow = r0 + gm0 + wr + mi * 16 + q * 4 + r;  // global row
      int b = grow / 50;
      int n = grow - b * 50;
      float keep = (n < mask_s[b]) ? 1.f : 0.f;
#pragma unroll
      for (int ni = 0; ni < 4; ++ni) {
        int gcol = gn0 + wc + ni * 16 + mcol;
        float v = fmaxf(acc[mi][ni][r] + bias[gcol], 0.f) * keep;
        if (gcol < 300) outp[(size_t)grow * 600 + 300 + gcol] = v;
      }
    }
}

// ============================ attention ============================
// One block per batch (chunk-local). P1: logits = fa4 @ fa3^T, 3-pass hi/lo
// (MFMA, 64x64, K=1216). P2: mask + softmax (wave per row). P3: msg = adj @
// fa5o (K=64, 1-pass).
__global__ __launch_bounds__(256) void k_attn(const u16* fa3h, const u16* fa3l,
    const u16* fa4h, const u16* fa4l, const u16* fa5o, const int* mask_s,
    float* adj_out, u16* msg, int b0) {
  __shared__ __align__(16) u16 stg[4096];  // 8KB staging (A:0..2047, B:2048..)
  __shared__ float Ssc[64 * 64];           // logits -> adj
  const int bl = blockIdx.x;               // chunk-local batch
  const int bg = b0 + bl;                  // global batch
  const int tid = threadIdx.x, lane = tid & 63, wv = tid >> 6;
  const int mrow = lane & 15, q = lane >> 4;
  const size_t base = (size_t)bl * 50 * 1216;

  // ---- phase 1: logits (3-pass: h*h, l*h, h*l) ----
  {
    const int srow = tid >> 2;
    const int srcRow = srow < 50 ? srow : 49;  // clamp; rows>=50 discarded
    const size_t gsoff = base + (size_t)srcRow * 1216 + (tid & 3) * 8;
    u16* lA = stg + tid * 8;
    u16* lB = stg + 2048 + tid * 8;
    f32x4 acc[4] = {};
    for (int p = 0; p < 3; ++p) {
      const u16* Ap = (p == 1) ? fa4l : fa4h;
      const u16* Bp = (p == 2) ? fa3l : fa3h;
      for (int t = 0; t < 38; ++t) {
        __syncthreads();
        async16(Ap + gsoff + t * 32, lA);
        async16(Bp + gsoff + t * 32, lB);
        __syncthreads();
        bf16x8 af = *(const bf16x8*)(stg + (wv * 16 + mrow) * 32 + q * 8);
#pragma unroll
        for (int ni = 0; ni < 4; ++ni) {
          bf16x8 bv = *(const bf16x8*)(stg + 2048 + (ni * 16 + mrow) * 32 + q * 8);
          acc[ni] =
              __builtin_amdgcn_mfma_f32_16x16x32_bf16(af, bv, acc[ni], 0, 0, 0);
        }
      }
    }
#pragma unroll
    for (int ni = 0; ni < 4; ++ni)
#pragma unroll
      for (int r = 0; r < 4; ++r)
        Ssc[(wv * 16 + q * 4 + r) * 64 + ni * 16 + mrow] = acc[ni][r];
  }
  __syncthreads();

  // ---- phase 2: mask + softmax, write adj ----
  {
    const int mk = mask_s[bg];
    for (int n = wv; n < 50; n += 4) {
      int mm = lane;
      float v = -__builtin_inff();
      if (mm < 50) {
        int mx2 = n > mm ? n : mm;
        bool valid = (mx2 < mk) || (n >= mk);
        if (mm == n) valid = false;
        if (n == 0 && mm == 0 && mk == 1) valid = true;
        if (valid) v = Ssc[n * 64 + mm];
      }
      float mx = v;
      for (int o = 32; o > 0; o >>= 1) mx = fmaxf(mx, __shfl_down(mx, o));
      mx = __shfl(mx, 0);
      float e = __expf(v - mx);  // -inf -> 0
      float sm = e;
      for (int o = 32; o > 0; o >>= 1) sm += __shfl_down(sm, o);
      sm = __shfl(sm, 0);
      float pv = e / sm;
      if (mm < 50) {
        adj_out[((size_t)bg * 50 + n) * 50 + mm] = pv;
        Ssc[n * 64 + mm] = pv;
      } else {
        Ssc[n * 64 + mm] = 0.f;  // zero K-pad cols for phase 3
      }
    }
  }
  __syncthreads();

  // ---- phase 3: msg[n][d] = sum_m adj[n][m] * fa5o[m][d] ----
  {
    const int c0 = tid, c1 = tid + 256;  // stg [64 m][64 d] = 512 chunks
    const int m0 = c0 >> 3, d0 = (c0 & 7) * 8;
    const int m1 = c1 >> 3, d1 = (c1 & 7) * 8;
    const size_t g0 = base + (size_t)(m0 < 50 ? m0 : 49) * 1216 + d0;
    const size_t g1 = base + (size_t)(m1 < 50 ? m1 : 49) * 1216 + d1;
    for (int dt = 0; dt < 19; ++dt) {
      __syncthreads();
      async16(fa5o + g0 + dt * 64, stg + c0 * 8);
      async16(fa5o + g1 + dt * 64, stg + c1 * 8);
      __syncthreads();
      f32x4 a3[4] = {};
#pragma unroll
      for (int ks = 0; ks < 2; ++ks) {
        bf16x8 af;
#pragma unroll
        for (int j = 0; j < 8; ++j)
          af[j] = (__bf16)Ssc[(wv * 16 + mrow) * 64 + ks * 32 + q * 8 + j];
#pragma unroll
        for (int ni = 0; ni < 4; ++ni) {
          bf16x8 bv;
#pragma unroll
          for (int j = 0; j < 8; ++j)
            bv[j] = *(const __bf16*)(stg + (ks * 32 + q * 8 + j) * 64 + ni * 16 + mrow);
          a3[ni] = __builtin_amdgcn_mfma_f32_16x16x32_bf16(af, bv, a3[ni], 0, 0, 0);
        }
      }
#pragma unroll
      for (int ni = 0; ni < 4; ++ni)
#pragma unroll
        for (int r = 0; r < 4; ++r) {
          int n = wv * 16 + q * 4 + r;
          if (n < 50)
            msg[((size_t)bl * 50 + n) * 1216 + dt * 64 + ni * 16 + mrow] =
                f2bf(a3[ni][r]);
        }
    }
  }
}

// d_out cols 0..299 = s * mask  (full problem, not chunked)
__global__ void k_write_s(const float* s, const int* mask_s, float* outp) {
  long i = (long)blockIdx.x * 256 + threadIdx.x;
  if (i >= 7680000L) return;
  int rn = (int)(i / 300);
  int c = (int)(i - (long)rn * 300);
  int b = rn / 50;
  int n = rn - b * 50;
  outp[(size_t)rn * 600 + c] = (n < mask_s[b]) ? s[i] : 0.f;
}

// ============================ host ============================
extern "C" void kernel_launch(void* const* d_in, const int* in_sizes, int n_in,
                              void* d_out_, int out_size, void* d_ws,
                              size_t ws_size, hipStream_t stream) {
  (void)in_sizes; (void)n_in; (void)out_size;
  const float* l_in = (const float*)d_in[0];
  const float* s_in = (const float*)d_in[1];
  const float* ps   = (const float*)d_in[2];
  const int*   msk  = (const int*)d_in[3];
  const float* bbw  = (const float*)d_in[4];
  const float* bbb  = (const float*)d_in[5];
  const float* fa1w = (const float*)d_in[6];
  const float* fa1b = (const float*)d_in[7];
  const float* fa2w = (const float*)d_in[8];
  const float* fa2b = (const float*)d_in[9];
  const float* fa3w = (const float*)d_in[10];
  const float* fa3b = (const float*)d_in[11];
  const float* fa4w = (const float*)d_in[12];
  const float* fa4b = (const float*)d_in[13];
  const float* fa5w = (const float*)d_in[14];
  const float* fa5b = (const float*)d_in[15];
  const float* lp1w = (const float*)d_in[16];
  const float* lp1b = (const float*)d_in[17];
  const float* lp2w = (const float*)d_in[18];
  const float* lp2b = (const float*)d_in[19];
  const float* outw = (const float*)d_in[20];
  const float* outb = (const float*)d_in[21];
  float* outp = (float*)d_out_;

  char* wsb = (char*)d_ws;
  size_t off = 0;
  auto alloc = [&](size_t bytes) -> char* {
    char* p = wsb + off;
    off = (off + bytes + 255) & ~(size_t)255;
    return p;
  };
  // ---- persistent (~31 MB) ----
  u16*   l_hi   = (u16*)alloc(512ull * 2048 * 2);
  u16*   l_lo   = (u16*)alloc(512ull * 2048 * 2);
  u16*   Wout   = (u16*)alloc(384ull * 1216 * 2);
  float* b_fa12 = (float*)alloc(1280 * 4);
  float* b_fa34 = (float*)alloc(2560 * 4);
  float* b_fa5  = (float*)alloc(1280 * 4);
  float* b_lp   = (float*)alloc(2560 * 4);
  float* b_out  = (float*)alloc(384 * 4);
  float* lp_o   = (float*)alloc(512ull * 2560 * 4);
  // weight slab, time-shared: lp weights (21.0 MB) -> fa* weights (19.7 MB).
  // Safe: k_gemm_lp completes (stream order) before fa* packs overwrite.
  u16*   slab   = (u16*)alloc(10485760ull * 2);
  u16* Wlph   = slab;                  // 2560x2048
  u16* Wlpl   = slab + 5242880;        // 2560x2048
  u16* Wfa1h  = slab;                  // 640x640
  u16* Wfa1l  = slab + 409600;
  u16* Wfa2h  = slab + 819200;
  u16* Wfa2l  = slab + 1228800;
  u16* Wfa34h = slab + 1638400;        // 2560x1280
  u16* Wfa34l = slab + 4915200;        // 2560x1280
  u16* Wfa5h  = slab + 8192000;        // 1280x1280

  // ---- choose chunk rows RN: largest of {25600,12800,6400,3200} that fits.
  // per-row: Chi 2560 + Clo 2560 + R2 2560 + (fa3h/l, fa4h/l) 4*2432 = 17408 B
  // ws_size==0 (unreported) -> assume generous scratch.
  size_t ws_eff = ws_size ? ws_size : (size_t)512 * 1024 * 1024;
  long RN = 3200;
  const long opts[4] = {25600, 12800, 6400, 3200};
  for (int i = 0; i < 4; ++i) {
    size_t need = off + (size_t)17408 * opts[i] + 8 * 256;
    if (need <= ws_eff) { RN = opts[i]; break; }
  }
  u16*  Chi  = (u16*)alloc((size_t)RN * 1280 * 2);
  u16*  Clo  = (u16*)alloc((size_t)RN * 1280 * 2);
  char* R2   = alloc((size_t)RN * 2560);  // fa1o f32, later fa5o bf16
  u16*  fa3h = (u16*)alloc((size_t)RN * 1216 * 2);
  u16*  fa3l = (u16*)alloc((size_t)RN * 1216 * 2);
  u16*  fa4h = (u16*)alloc((size_t)RN * 1216 * 2);
  u16*  fa4l = (u16*)alloc((size_t)RN * 1216 * 2);
  float* fa1o = (float*)R2;
  u16*   fa5o = (u16*)R2;
  u16*   msg  = Chi;  // combined dead after fa5 GEMM; reuse for messages_in
  float* adj_o = outp + 15360000;

  dim3 T(256);
  // biases (padded)
  k_pack_bias<<<dim3(3), T, 0, stream>>>(fa1b, 600, b_fa12, 640);
  k_pack_bias<<<dim3(3), T, 0, stream>>>(fa2b, 600, b_fa12 + 640, 640);
  k_pack_bias<<<dim3(5), T, 0, stream>>>(fa3b, 1200, b_fa34, 1280);
  k_pack_bias<<<dim3(5), T, 0, stream>>>(fa4b, 1200, b_fa34 + 1280, 1280);
  k_pack_bias<<<dim3(5), T, 0, stream>>>(fa5b, 1200, b_fa5, 1280);
  k_pack_bias<<<dim3(5), T, 0, stream>>>(lp1b, 1200, b_lp, 1280);
  k_pack_bias<<<dim3(5), T, 0, stream>>>(lp2b, 1200, b_lp + 1280, 1280);
  k_pack_bias<<<dim3(2), T, 0, stream>>>(outb, 300, b_out, 384);

  auto packw = [&](const float* src, int n, int k, u16* hi, u16* lo, int KP,
                   long total, int gap) {
    k_pack_w<<<dim3((unsigned)((total + 255) / 256)), T, 0, stream>>>(
        src, n, k, hi, lo, KP, total, gap);
  };
  // static packs
  packw(l_in, 512, 2048, l_hi, l_lo, 2048, 512L * 2048, 0);
  packw(outw, 300, 1200, Wout, nullptr, 1216, 384L * 1216, 0);

  // lp stage: pack lp weights into slab, run lp GEMM (whole batch, once)
  packw(lp1w, 1200, 2048, Wlph, Wlpl, 2048, 1280L * 2048, 0);
  packw(lp2w, 1200, 2048, Wlph + 1280 * 2048, Wlpl + 1280 * 2048, 2048,
        1280L * 2048, 0);
  k_gemm_lp<<<dim3(20, 4), T, 0, stream>>>(l_hi, l_lo, Wlph, Wlpl, b_lp, lp_o);

  // fa weights into slab (overwrites lp weights — dead after k_gemm_lp)
  packw(fa1w, 600, 600, Wfa1h, Wfa1l, 640, 640L * 640, 0);
  packw(fa2w, 600, 600, Wfa2h, Wfa2l, 640, 640L * 640, 0);
  packw(fa3w, 1200, 1200, Wfa34h, Wfa34l, 1280, 1280L * 1280, 1);
  packw(fa4w, 1200, 1200, Wfa34h + 1638400, Wfa34l + 1638400, 1280,
        1280L * 1280, 1);
  packw(fa5w, 1200, 1200, Wfa5h, nullptr, 1280, 1280L * 1280, 1);

  // ---- chunk loop ----
  const int nch = (int)(25600 / RN);
  const unsigned gy = (unsigned)(RN / 128);
  for (int c = 0; c < nch; ++c) {
    const int r0 = (int)(c * RN);
    const int b0 = r0 / 50;
    k_bb<<<dim3((unsigned)RN), T, 0, stream>>>(s_in + (size_t)r0 * 300,
                                               ps + (size_t)r0 * 4, bbw, bbb,
                                               Chi, Clo);
    k_gemm_fa1<<<dim3(5, gy), T, 0, stream>>>(Chi, Clo, Wfa1h, Wfa1l, b_fa12,
                                              fa1o);
    k_gemm_fa2<<<dim3(5, gy), T, 0, stream>>>(Chi, Clo, Wfa2h, Wfa2l,
                                              b_fa12 + 640, fa1o, Chi, Clo);
    k_gemm_fa34<<<dim3(20, gy), T, 0, stream>>>(Chi, Clo, Wfa34h, Wfa34l,
                                                b_fa34, lp_o, fa3h, fa3l,
                                                fa4h, fa4l, r0);
    k_gemm_fa5<<<dim3(10, gy), T, 0, stream>>>(Chi, Wfa5h, b_fa5, lp_o, fa5o,
                                               r0);
    k_attn<<<dim3((unsigned)(RN / 50)), T, 0, stream>>>(fa3h, fa3l, fa4h, fa4l,
                                                        fa5o, msk, adj_o, msg,
                                                        b0);
    k_gemm_out<<<dim3(3, gy), T, 0, stream>>>(msg, Wout, b_out, msk, outp, r0);
  }
  k_write_s<<<dim3(30000), T, 0, stream>>>(s_in, msk, outp);
}

// Round 6
// 1867.019 us; speedup vs baseline: 1.0190x; 1.0190x over previous
//
#include <hip/hip_runtime.h>
#include <stdint.h>

typedef unsigned short u16;
typedef unsigned int u32;
typedef __attribute__((ext_vector_type(8))) __bf16 bf16x8;
typedef __attribute__((ext_vector_type(4))) float f32x4;

#define DEVINL static __device__ __forceinline__

// round-to-nearest-even f32 -> bf16
DEVINL u16 f2bf(float x) {
  u32 u = __float_as_uint(x);
  return (u16)((u + (((u >> 16) & 1u) + 0x7fffu)) >> 16);
}
DEVINL float bf2f(u16 h) { return __uint_as_float(((u32)h) << 16); }

// async global->LDS, 16B per lane. HW semantics: wave-uniform base + lane*16.
DEVINL void async16(const void* g, void* l) {
  void* g2 = const_cast<void*>(g);
  __builtin_amdgcn_global_load_lds((__attribute__((address_space(1))) void*)g2,
                                   (__attribute__((address_space(3))) void*)l,
                                   16, 0, 0);
}

// ============================ pack kernels ============================
__global__ void k_pack_w(const float* src, int n, int k, u16* hi, u16* lo,
                         int KP, long total, int gap) {
  long i = (long)blockIdx.x * 256 + threadIdx.x;
  if (i >= total) return;
  int r = (int)(i / KP);
  int c = (int)(i - (long)r * KP);
  int sc = c;
  bool ok = (r < n);
  if (gap) {
    if (c >= 600 && c < 640) ok = false;
    else if (c >= 640) sc = c - 40;
  }
  if (sc >= k) ok = false;
  float x = ok ? src[(size_t)r * k + sc] : 0.f;
  u16 h = f2bf(x);
  hi[i] = h;
  if (lo) lo[i] = f2bf(x - bf2f(h));
}

__global__ void k_pack_bias(const float* src, int n, float* dst, int NP) {
  int i = blockIdx.x * 256 + threadIdx.x;
  if (i < NP) dst[i] = (i < n) ? src[i] : 0.f;
}

// ============ bb_process + concat(s, bb) -> combined[:, 0:640] ============
__global__ void k_bb(const float* s_c, const float* ps_c, const float* bb_w,
                     const float* bb_b, u16* Chi, u16* Clo) {
  int rn = blockIdx.x;
  const float* p = ps_c + (size_t)rn * 4;
  float p0 = p[0], p1 = p[1], p2 = p[2], p3 = p[3];
  float sz0 = p2 - p0, sz1 = p3 - p1;
  float bin[10];
  bin[0] = p0; bin[1] = p1; bin[2] = p2; bin[3] = p3;
  bin[4] = sz0; bin[5] = sz1;
  bin[6] = p0 + 0.5f * sz0; bin[7] = p1 + 0.5f * sz1;
  bin[8] = sz0 * sz1; bin[9] = sz0 / (sz1 + 1e-14f);
  for (int c = threadIdx.x; c < 640; c += 256) {
    float x = 0.f;
    if (c < 300) {
      x = s_c[(size_t)rn * 300 + c];
    } else if (c < 600) {
      int j = c - 300;
      float a = bb_b[j];
      const float* wr = bb_w + j * 10;
#pragma unroll
      for (int kk = 0; kk < 10; ++kk) a += bin[kk] * wr[kk];
      x = fmaxf(a, 0.f);
    }
    u16 h = f2bf(x);
    Chi[(size_t)rn * 1280 + c] = h;
    Clo[(size_t)rn * 1280 + c] = f2bf(x - bf2f(h));
  }
}

// ============================ GEMM cores ============================
// 128x128 tile, BK=32, 4 waves x (4x4) 16x16x32 bf16 MFMA, C = A @ W^T.
DEVINL void gemm_core(const u16* const Aph[3], const u16* const Bph[3],
                      int lda, int ldw, int ksteps, int passes,
                      u16* As, u16* Bs, f32x4 (&acc)[4][4]) {
  const int tid = threadIdx.x;
  const int lane = tid & 63;
  const int wv = tid >> 6;
  const int wr = (wv >> 1) * 64;
  const int wc = (wv & 1) * 64;
  const int mrow = lane & 15;
  const int q = lane >> 4;

  const int c0 = tid, c1 = tid + 256;
  const long aoff0 = (long)(c0 >> 2) * lda + (c0 & 3) * 8;
  const long aoff1 = (long)(c1 >> 2) * lda + (c1 & 3) * 8;
  const long boff0 = (long)(c0 >> 2) * ldw + (c0 & 3) * 8;
  const long boff1 = (long)(c1 >> 2) * ldw + (c1 & 3) * 8;
  u16* lA0 = As + c0 * 8; u16* lA1 = As + c1 * 8;
  u16* lB0 = Bs + c0 * 8; u16* lB1 = Bs + c1 * 8;

  const int aF = (wr + mrow) * 32 + q * 8;
  const int bF = (wc + mrow) * 32 + q * 8;

  for (int p = 0; p < passes; ++p) {
    const u16* Ab = Aph[p];
    const u16* Bb = Bph[p];
    for (int t = 0; t < ksteps; ++t) {
      const u16* ga = Ab + t * 32;
      const u16* gb = Bb + t * 32;
      __syncthreads();
      async16(ga + aoff0, lA0);
      async16(ga + aoff1, lA1);
      async16(gb + boff0, lB0);
      async16(gb + boff1, lB1);
      __syncthreads();
      bf16x8 af[4], bv[4];
#pragma unroll
      for (int i = 0; i < 4; ++i) af[i] = *(const bf16x8*)(As + aF + i * 512);
#pragma unroll
      for (int i = 0; i < 4; ++i) bv[i] = *(const bf16x8*)(Bs + bF + i * 512);
#pragma unroll
      for (int i = 0; i < 4; ++i)
#pragma unroll
        for (int j = 0; j < 4; ++j)
          acc[i][j] = __builtin_amdgcn_mfma_f32_16x16x32_bf16(af[i], bv[j],
                                                              acc[i][j], 0, 0, 0);
    }
  }
}

// dual-B variant: one A staging, two weight matrices, two accumulators.
DEVINL void gemm_core2(const u16* const Aph[3], const u16* const B1ph[3],
                       const u16* const B2ph[3], int lda, int ldw, int ksteps,
                       u16* As, u16* B1s, u16* B2s, f32x4 (&a1)[4][4],
                       f32x4 (&a2)[4][4]) {
  const int tid = threadIdx.x;
  const int lane = tid & 63;
  const int wv = tid >> 6;
  const int wr = (wv >> 1) * 64;
  const int wc = (wv & 1) * 64;
  const int mrow = lane & 15;
  const int q = lane >> 4;

  const int c0 = tid, c1 = tid + 256;
  const long aoff0 = (long)(c0 >> 2) * lda + (c0 & 3) * 8;
  const long aoff1 = (long)(c1 >> 2) * lda + (c1 & 3) * 8;
  const long boff0 = (long)(c0 >> 2) * ldw + (c0 & 3) * 8;
  const long boff1 = (long)(c1 >> 2) * ldw + (c1 & 3) * 8;
  u16* lA0 = As + c0 * 8;  u16* lA1 = As + c1 * 8;
  u16* l10 = B1s + c0 * 8; u16* l11 = B1s + c1 * 8;
  u16* l20 = B2s + c0 * 8; u16* l21 = B2s + c1 * 8;

  const int aF = (wr + mrow) * 32 + q * 8;
  const int bF = (wc + mrow) * 32 + q * 8;

  for (int p = 0; p < 3; ++p) {
    const u16* Ab = Aph[p];
    const u16* B1b = B1ph[p];
    const u16* B2b = B2ph[p];
    for (int t = 0; t < ksteps; ++t) {
      const u16* ga = Ab + t * 32;
      const u16* g1 = B1b + t * 32;
      const u16* g2 = B2b + t * 32;
      __syncthreads();
      async16(ga + aoff0, lA0);
      async16(ga + aoff1, lA1);
      async16(g1 + boff0, l10);
      async16(g1 + boff1, l11);
      async16(g2 + boff0, l20);
      async16(g2 + boff1, l21);
      __syncthreads();
      bf16x8 af[4], b1v[4], b2v[4];
#pragma unroll
      for (int i = 0; i < 4; ++i) af[i] = *(const bf16x8*)(As + aF + i * 512);
#pragma unroll
      for (int i = 0; i < 4; ++i) b1v[i] = *(const bf16x8*)(B1s + bF + i * 512);
#pragma unroll
      for (int i = 0; i < 4; ++i) b2v[i] = *(const bf16x8*)(B2s + bF + i * 512);
#pragma unroll
      for (int i = 0; i < 4; ++i)
#pragma unroll
        for (int j = 0; j < 4; ++j)
          a1[i][j] = __builtin_amdgcn_mfma_f32_16x16x32_bf16(af[i], b1v[j],
                                                             a1[i][j], 0, 0, 0);
#pragma unroll
      for (int i = 0; i < 4; ++i)
#pragma unroll
        for (int j = 0; j < 4; ++j)
          a2[i][j] = __builtin_amdgcn_mfma_f32_16x16x32_bf16(af[i], b2v[j],
                                                             a2[i][j], 0, 0, 0);
    }
  }
}

#define GEMM_PROLOGUE(LDA, LDW)                                         \
  __shared__ __align__(16) u16 As[4096], Bs[4096];                      \
  const u16* Aph[3]; const u16* Bph[3];                                 \
  const size_t arow = (size_t)blockIdx.y * 128 * (LDA);                 \
  const size_t wrow = (size_t)blockIdx.x * 128 * (LDW);                 \
  f32x4 acc[4][4] = {};

#define GEMM_EPI_IDX                                                    \
  const int lane = threadIdx.x & 63, wv = threadIdx.x >> 6;             \
  const int wr = (wv >> 1) * 64, wc = (wv & 1) * 64;                    \
  const int mcol = lane & 15, q = lane >> 4;                            \
  const int gm0 = blockIdx.y * 128, gn0 = blockIdx.x * 128;

// fa1+fa2 fused, 3-pass dual-B: y = relu(A@W1^T+b1)*relu(A@W2^T+b2)
// -> combined[:, 640+gcol] hi/lo. A = combined[:, :640] (cols 0..639 only;
// writes go to cols 640..1279 — disjoint, safe within/across blocks).
__global__ __launch_bounds__(256) void k_gemm_fa12(const u16* Ah, const u16* Al,
    const u16* W1h, const u16* W1l, const u16* W2h, const u16* W2l,
    const float* bias, u16* Chi, u16* Clo) {
  __shared__ __align__(16) u16 As[4096], B1s[4096], B2s[4096];
  const size_t arow = (size_t)blockIdx.y * 128 * 1280;
  const size_t wrow = (size_t)blockIdx.x * 128 * 640;
  const u16* Aph[3]  = {Ah + arow, Al + arow, Ah + arow};
  const u16* B1ph[3] = {W1h + wrow, W1h + wrow, W1l + wrow};
  const u16* B2ph[3] = {W2h + wrow, W2h + wrow, W2l + wrow};
  f32x4 a1[4][4] = {}, a2[4][4] = {};
  gemm_core2(Aph, B1ph, B2ph, 1280, 640, 20, As, B1s, B2s, a1, a2);
  GEMM_EPI_IDX
#pragma unroll
  for (int mi = 0; mi < 4; ++mi)
#pragma unroll
    for (int r = 0; r < 4; ++r) {
      int grow = gm0 + wr + mi * 16 + q * 4 + r;
#pragma unroll
      for (int ni = 0; ni < 4; ++ni) {
        int gcol = gn0 + wc + ni * 16 + mcol;
        float v1 = fmaxf(a1[mi][ni][r] + bias[gcol], 0.f);
        float v2 = fmaxf(a2[mi][ni][r] + bias[640 + gcol], 0.f);
        float y = v1 * v2;
        u16 h = f2bf(y);
        Chi[(size_t)grow * 1280 + 640 + gcol] = h;
        Clo[(size_t)grow * 1280 + 640 + gcol] = f2bf(y - bf2f(h));
      }
    }
}

// lp: [512,2048] @ [2560,2048]^T, 3-pass, relu -> f32 [512,2560]
__global__ __launch_bounds__(256) void k_gemm_lp(const u16* Ah, const u16* Al,
    const u16* Wh, const u16* Wl, const float* bias, float* outp) {
  GEMM_PROLOGUE(2048, 2048)
  Aph[0] = Ah + arow; Aph[1] = Al + arow; Aph[2] = Ah + arow;
  Bph[0] = Wh + wrow; Bph[1] = Wh + wrow; Bph[2] = Wl + wrow;
  gemm_core(Aph, Bph, 2048, 2048, 64, 3, As, Bs, acc);
  GEMM_EPI_IDX
#pragma unroll
  for (int mi = 0; mi < 4; ++mi)
#pragma unroll
    for (int r = 0; r < 4; ++r) {
      int grow = gm0 + wr + mi * 16 + q * 4 + r;
#pragma unroll
      for (int ni = 0; ni < 4; ++ni) {
        int gcol = gn0 + wc + ni * 16 + mcol;
        outp[(size_t)grow * 2560 + gcol] = fmaxf(acc[mi][ni][r] + bias[gcol], 0.f);
      }
    }
}

// fa3+fa4+fa5 fused. x-tiles 0..19: fa34 (3-pass hi/lo, N=2560); x-tiles
// 20..29: fa5 (1-pass, N=1280). Block-uniform branch; identical arithmetic
// to the previous separate kernels.
__global__ __launch_bounds__(256) void k_gemm_fa345(const u16* Ah, const u16* Al,
    const u16* Wh, const u16* Wl, const u16* W5h, const float* b34,
    const float* b5, const float* lp_o, u16* fa3h, u16* fa3l, u16* fa4h,
    u16* fa4l, u16* fa5o, int r0) {
  __shared__ __align__(16) u16 As[4096], Bs[4096];
  const u16* Aph[3]; const u16* Bph[3];
  const size_t arow = (size_t)blockIdx.y * 128 * 1280;
  const int gn0 = blockIdx.x * 128;
  f32x4 acc[4][4] = {};
  int passes;
  if (gn0 < 2560) {
    const size_t wrow = (size_t)gn0 * 1280;
    Aph[0] = Ah + arow; Aph[1] = Al + arow; Aph[2] = Ah + arow;
    Bph[0] = Wh + wrow; Bph[1] = Wh + wrow; Bph[2] = Wl + wrow;
    passes = 3;
  } else {
    const size_t wrow = (size_t)(gn0 - 2560) * 1280;
    Aph[0] = Ah + arow; Aph[1] = Ah + arow; Aph[2] = Ah + arow;
    Bph[0] = W5h + wrow; Bph[1] = Bph[0]; Bph[2] = Bph[0];
    passes = 1;
  }
  gemm_core(Aph, Bph, 1280, 1280, 40, passes, As, Bs, acc);
  const int lane = threadIdx.x & 63, wv = threadIdx.x >> 6;
  const int wr = (wv >> 1) * 64, wc = (wv & 1) * 64;
  const int mcol = lane & 15, q = lane >> 4;
  const int gm0 = blockIdx.y * 128;
  if (gn0 < 2560) {
    const int seg = (gn0 >= 1280);
    u16* dsth = seg ? fa4h : fa3h;
    u16* dstl = seg ? fa4l : fa3l;
#pragma unroll
    for (int mi = 0; mi < 4; ++mi)
#pragma unroll
      for (int r = 0; r < 4; ++r) {
        int grow = gm0 + wr + mi * 16 + q * 4 + r;
        int b = (r0 + grow) / 50;
        const float* lpb = lp_o + (size_t)b * 2560;
#pragma unroll
        for (int ni = 0; ni < 4; ++ni) {
          int gcol = gn0 + wc + ni * 16 + mcol;
          int c = seg ? gcol - 1280 : gcol;
          float v = fmaxf(acc[mi][ni][r] + b34[gcol], 0.f);
          if (!seg) v *= lpb[c];
          if (c < 1216) {
            u16 h = f2bf(v);
            dsth[(size_t)grow * 1216 + c] = h;
            dstl[(size_t)grow * 1216 + c] = f2bf(v - bf2f(h));
          }
        }
      }
  } else {
#pragma unroll
    for (int mi = 0; mi < 4; ++mi)
#pragma unroll
      for (int r = 0; r < 4; ++r) {
        int grow = gm0 + wr + mi * 16 + q * 4 + r;
        int b = (r0 + grow) / 50;
        const float* lpb = lp_o + (size_t)b * 2560 + 1280;
#pragma unroll
        for (int ni = 0; ni < 4; ++ni) {
          int gcol = (gn0 - 2560) + wc + ni * 16 + mcol;
          float v = fmaxf(acc[mi][ni][r] + b5[gcol], 0.f) * lpb[gcol];
          if (gcol < 1216) fa5o[(size_t)grow * 1216 + gcol] = f2bf(v);
        }
      }
  }
}

// out FC, 1-pass: messages = relu(msg@outw^T+b), masked, -> d_out cols 300..599
__global__ __launch_bounds__(256) void k_gemm_out(const u16* A, const u16* Wh,
    const float* bias, const int* mask_s, float* outp, int r0) {
  GEMM_PROLOGUE(1216, 1216)
  Aph[0] = A + arow; Aph[1] = A + arow; Aph[2] = A + arow;
  Bph[0] = Wh + wrow; Bph[1] = Wh + wrow; Bph[2] = Wh + wrow;
  gemm_core(Aph, Bph, 1216, 1216, 38, 1, As, Bs, acc);
  GEMM_EPI_IDX
#pragma unroll
  for (int mi = 0; mi < 4; ++mi)
#pragma unroll
    for (int r = 0; r < 4; ++r) {
      int grow = r0 + gm0 + wr + mi * 16 + q * 4 + r;  // global row
      int b = grow / 50;
      int n = grow - b * 50;
      float keep = (n < mask_s[b]) ? 1.f : 0.f;
#pragma unroll
      for (int ni = 0; ni < 4; ++ni) {
        int gcol = gn0 + wc + ni * 16 + mcol;
        float v = fmaxf(acc[mi][ni][r] + bias[gcol], 0.f) * keep;
        if (gcol < 300) outp[(size_t)grow * 600 + 300 + gcol] = v;
      }
    }
}

// ============================ attention ============================
__global__ __launch_bounds__(256) void k_attn(const u16* fa3h, const u16* fa3l,
    const u16* fa4h, const u16* fa4l, const u16* fa5o, const int* mask_s,
    float* adj_out, u16* msg, int b0) {
  __shared__ __align__(16) u16 stg[4096];
  __shared__ float Ssc[64 * 64];
  const int bl = blockIdx.x;
  const int bg = b0 + bl;
  const int tid = threadIdx.x, lane = tid & 63, wv = tid >> 6;
  const int mrow = lane & 15, q = lane >> 4;
  const size_t base = (size_t)bl * 50 * 1216;

  // ---- phase 1: logits (3-pass: h*h, l*h, h*l) ----
  {
    const int srow = tid >> 2;
    const int srcRow = srow < 50 ? srow : 49;
    const size_t gsoff = base + (size_t)srcRow * 1216 + (tid & 3) * 8;
    u16* lA = stg + tid * 8;
    u16* lB = stg + 2048 + tid * 8;
    f32x4 acc[4] = {};
    for (int p = 0; p < 3; ++p) {
      const u16* Ap = (p == 1) ? fa4l : fa4h;
      const u16* Bp = (p == 2) ? fa3l : fa3h;
      for (int t = 0; t < 38; ++t) {
        __syncthreads();
        async16(Ap + gsoff + t * 32, lA);
        async16(Bp + gsoff + t * 32, lB);
        __syncthreads();
        bf16x8 af = *(const bf16x8*)(stg + (wv * 16 + mrow) * 32 + q * 8);
#pragma unroll
        for (int ni = 0; ni < 4; ++ni) {
          bf16x8 bv = *(const bf16x8*)(stg + 2048 + (ni * 16 + mrow) * 32 + q * 8);
          acc[ni] =
              __builtin_amdgcn_mfma_f32_16x16x32_bf16(af, bv, acc[ni], 0, 0, 0);
        }
      }
    }
#pragma unroll
    for (int ni = 0; ni < 4; ++ni)
#pragma unroll
      for (int r = 0; r < 4; ++r)
        Ssc[(wv * 16 + q * 4 + r) * 64 + ni * 16 + mrow] = acc[ni][r];
  }
  __syncthreads();

  // ---- phase 2: mask + softmax, write adj ----
  {
    const int mk = mask_s[bg];
    for (int n = wv; n < 50; n += 4) {
      int mm = lane;
      float v = -__builtin_inff();
      if (mm < 50) {
        int mx2 = n > mm ? n : mm;
        bool valid = (mx2 < mk) || (n >= mk);
        if (mm == n) valid = false;
        if (n == 0 && mm == 0 && mk == 1) valid = true;
        if (valid) v = Ssc[n * 64 + mm];
      }
      float mx = v;
      for (int o = 32; o > 0; o >>= 1) mx = fmaxf(mx, __shfl_down(mx, o));
      mx = __shfl(mx, 0);
      float e = __expf(v - mx);
      float sm = e;
      for (int o = 32; o > 0; o >>= 1) sm += __shfl_down(sm, o);
      sm = __shfl(sm, 0);
      float pv = e / sm;
      if (mm < 50) {
        adj_out[((size_t)bg * 50 + n) * 50 + mm] = pv;
        Ssc[n * 64 + mm] = pv;
      } else {
        Ssc[n * 64 + mm] = 0.f;
      }
    }
  }
  __syncthreads();

  // ---- phase 3: msg[n][d] = sum_m adj[n][m] * fa5o[m][d] ----
  {
    const int c0 = tid, c1 = tid + 256;
    const int m0 = c0 >> 3, d0 = (c0 & 7) * 8;
    const int m1 = c1 >> 3, d1 = (c1 & 7) * 8;
    const size_t g0 = base + (size_t)(m0 < 50 ? m0 : 49) * 1216 + d0;
    const size_t g1 = base + (size_t)(m1 < 50 ? m1 : 49) * 1216 + d1;
    for (int dt = 0; dt < 19; ++dt) {
      __syncthreads();
      async16(fa5o + g0 + dt * 64, stg + c0 * 8);
      async16(fa5o + g1 + dt * 64, stg + c1 * 8);
      __syncthreads();
      f32x4 a3[4] = {};
#pragma unroll
      for (int ks = 0; ks < 2; ++ks) {
        bf16x8 af;
#pragma unroll
        for (int j = 0; j < 8; ++j)
          af[j] = (__bf16)Ssc[(wv * 16 + mrow) * 64 + ks * 32 + q * 8 + j];
#pragma unroll
        for (int ni = 0; ni < 4; ++ni) {
          bf16x8 bv;
#pragma unroll
          for (int j = 0; j < 8; ++j)
            bv[j] = *(const __bf16*)(stg + (ks * 32 + q * 8 + j) * 64 + ni * 16 + mrow);
          a3[ni] = __builtin_amdgcn_mfma_f32_16x16x32_bf16(af, bv, a3[ni], 0, 0, 0);
        }
      }
#pragma unroll
      for (int ni = 0; ni < 4; ++ni)
#pragma unroll
        for (int r = 0; r < 4; ++r) {
          int n = wv * 16 + q * 4 + r;
          if (n < 50)
            msg[((size_t)bl * 50 + n) * 1216 + dt * 64 + ni * 16 + mrow] =
                f2bf(a3[ni][r]);
        }
    }
  }
}

// d_out cols 0..299 = s * mask
__global__ void k_write_s(const float* s, const int* mask_s, float* outp) {
  long i = (long)blockIdx.x * 256 + threadIdx.x;
  if (i >= 7680000L) return;
  int rn = (int)(i / 300);
  int c = (int)(i - (long)rn * 300);
  int b = rn / 50;
  int n = rn - b * 50;
  outp[(size_t)rn * 600 + c] = (n < mask_s[b]) ? s[i] : 0.f;
}

// ============================ host ============================
extern "C" void kernel_launch(void* const* d_in, const int* in_sizes, int n_in,
                              void* d_out_, int out_size, void* d_ws,
                              size_t ws_size, hipStream_t stream) {
  (void)in_sizes; (void)n_in; (void)out_size;
  const float* l_in = (const float*)d_in[0];
  const float* s_in = (const float*)d_in[1];
  const float* ps   = (const float*)d_in[2];
  const int*   msk  = (const int*)d_in[3];
  const float* bbw  = (const float*)d_in[4];
  const float* bbb  = (const float*)d_in[5];
  const float* fa1w = (const float*)d_in[6];
  const float* fa1b = (const float*)d_in[7];
  const float* fa2w = (const float*)d_in[8];
  const float* fa2b = (const float*)d_in[9];
  const float* fa3w = (const float*)d_in[10];
  const float* fa3b = (const float*)d_in[11];
  const float* fa4w = (const float*)d_in[12];
  const float* fa4b = (const float*)d_in[13];
  const float* fa5w = (const float*)d_in[14];
  const float* fa5b = (const float*)d_in[15];
  const float* lp1w = (const float*)d_in[16];
  const float* lp1b = (const float*)d_in[17];
  const float* lp2w = (const float*)d_in[18];
  const float* lp2b = (const float*)d_in[19];
  const float* outw = (const float*)d_in[20];
  const float* outb = (const float*)d_in[21];
  float* outp = (float*)d_out_;

  char* wsb = (char*)d_ws;
  size_t off = 0;
  auto alloc = [&](size_t bytes) -> char* {
    char* p = wsb + off;
    off = (off + bytes + 255) & ~(size_t)255;
    return p;
  };
  // ---- persistent (~31 MB) ----
  u16*   l_hi   = (u16*)alloc(512ull * 2048 * 2);
  u16*   l_lo   = (u16*)alloc(512ull * 2048 * 2);
  u16*   Wout   = (u16*)alloc(384ull * 1216 * 2);
  float* b_fa12 = (float*)alloc(1280 * 4);
  float* b_fa34 = (float*)alloc(2560 * 4);
  float* b_fa5  = (float*)alloc(1280 * 4);
  float* b_lp   = (float*)alloc(2560 * 4);
  float* b_out  = (float*)alloc(384 * 4);
  float* lp_o   = (float*)alloc(512ull * 2560 * 4);
  // weight slab, time-shared: lp weights -> fa* weights (stream-ordered).
  u16*   slab   = (u16*)alloc(10485760ull * 2);
  u16* Wlph   = slab;                  // 2560x2048
  u16* Wlpl   = slab + 5242880;        // 2560x2048
  u16* Wfa1h  = slab;                  // 640x640
  u16* Wfa1l  = slab + 409600;
  u16* Wfa2h  = slab + 819200;
  u16* Wfa2l  = slab + 1228800;
  u16* Wfa34h = slab + 1638400;        // 2560x1280
  u16* Wfa34l = slab + 4915200;        // 2560x1280
  u16* Wfa5h  = slab + 8192000;        // 1280x1280

  // chunk rows RN: per-row Chi 2560 + Clo 2560 + fa5o 2432 + 4*2432 = 17280 B
  size_t ws_eff = ws_size ? ws_size : (size_t)512 * 1024 * 1024;
  long RN = 3200;
  const long opts[4] = {25600, 12800, 6400, 3200};
  for (int i = 0; i < 4; ++i) {
    size_t need = off + (size_t)17280 * opts[i] + 8 * 256;
    if (need <= ws_eff) { RN = opts[i]; break; }
  }
  u16*  Chi  = (u16*)alloc((size_t)RN * 1280 * 2);
  u16*  Clo  = (u16*)alloc((size_t)RN * 1280 * 2);
  u16*  fa5o = (u16*)alloc((size_t)RN * 1216 * 2);
  u16*  fa3h = (u16*)alloc((size_t)RN * 1216 * 2);
  u16*  fa3l = (u16*)alloc((size_t)RN * 1216 * 2);
  u16*  fa4h = (u16*)alloc((size_t)RN * 1216 * 2);
  u16*  fa4l = (u16*)alloc((size_t)RN * 1216 * 2);
  u16*  msg  = Chi;  // combined dead after fa345; reuse for messages_in
  float* adj_o = outp + 15360000;

  dim3 T(256);
  // biases (padded)
  k_pack_bias<<<dim3(3), T, 0, stream>>>(fa1b, 600, b_fa12, 640);
  k_pack_bias<<<dim3(3), T, 0, stream>>>(fa2b, 600, b_fa12 + 640, 640);
  k_pack_bias<<<dim3(5), T, 0, stream>>>(fa3b, 1200, b_fa34, 1280);
  k_pack_bias<<<dim3(5), T, 0, stream>>>(fa4b, 1200, b_fa34 + 1280, 1280);
  k_pack_bias<<<dim3(5), T, 0, stream>>>(fa5b, 1200, b_fa5, 1280);
  k_pack_bias<<<dim3(5), T, 0, stream>>>(lp1b, 1200, b_lp, 1280);
  k_pack_bias<<<dim3(5), T, 0, stream>>>(lp2b, 1200, b_lp + 1280, 1280);
  k_pack_bias<<<dim3(2), T, 0, stream>>>(outb, 300, b_out, 384);

  auto packw = [&](const float* src, int n, int k, u16* hi, u16* lo, int KP,
                   long total, int gap) {
    k_pack_w<<<dim3((unsigned)((total + 255) / 256)), T, 0, stream>>>(
        src, n, k, hi, lo, KP, total, gap);
  };
  // static packs
  packw(l_in, 512, 2048, l_hi, l_lo, 2048, 512L * 2048, 0);
  packw(outw, 300, 1200, Wout, nullptr, 1216, 384L * 1216, 0);

  // lp stage
  packw(lp1w, 1200, 2048, Wlph, Wlpl, 2048, 1280L * 2048, 0);
  packw(lp2w, 1200, 2048, Wlph + 1280 * 2048, Wlpl + 1280 * 2048, 2048,
        1280L * 2048, 0);
  k_gemm_lp<<<dim3(20, 4), T, 0, stream>>>(l_hi, l_lo, Wlph, Wlpl, b_lp, lp_o);

  // fa weights into slab (lp weights dead after k_gemm_lp)
  packw(fa1w, 600, 600, Wfa1h, Wfa1l, 640, 640L * 640, 0);
  packw(fa2w, 600, 600, Wfa2h, Wfa2l, 640, 640L * 640, 0);
  packw(fa3w, 1200, 1200, Wfa34h, Wfa34l, 1280, 1280L * 1280, 1);
  packw(fa4w, 1200, 1200, Wfa34h + 1638400, Wfa34l + 1638400, 1280,
        1280L * 1280, 1);
  packw(fa5w, 1200, 1200, Wfa5h, nullptr, 1280, 1280L * 1280, 1);

  // ---- chunk loop ----
  const int nch = (int)(25600 / RN);
  const unsigned gy = (unsigned)(RN / 128);
  for (int c = 0; c < nch; ++c) {
    const int r0 = (int)(c * RN);
    const int b0 = r0 / 50;
    k_bb<<<dim3((unsigned)RN), T, 0, stream>>>(s_in + (size_t)r0 * 300,
                                               ps + (size_t)r0 * 4, bbw, bbb,
                                               Chi, Clo);
    k_gemm_fa12<<<dim3(5, gy), T, 0, stream>>>(Chi, Clo, Wfa1h, Wfa1l, Wfa2h,
                                               Wfa2l, b_fa12, Chi, Clo);
    k_gemm_fa345<<<dim3(30, gy), T, 0, stream>>>(Chi, Clo, Wfa34h, Wfa34l,
                                                 Wfa5h, b_fa34, b_fa5, lp_o,
                                                 fa3h, fa3l, fa4h, fa4l, fa5o,
                                                 r0);
    k_attn<<<dim3((unsigned)(RN / 50)), T, 0, stream>>>(fa3h, fa3l, fa4h, fa4l,
                                                        fa5o, msk, adj_o, msg,
                                                        b0);
    k_gemm_out<<<dim3(3, gy), T, 0, stream>>>(msg, Wout, b_out, msk, outp, r0);
  }
  k_write_s<<<dim3(30000), T, 0, stream>>>(s_in, msk, outp);
}